// Round 12
// baseline (119.593 us; speedup 1.0000x reference)
//
#include <hip/hip_runtime.h>

#define NNODES 4096
#define HID 256
#define NG 16
#define NH 8
#define HD 32
#define LN_EPS 1e-5f
// (1/sqrt(32)) * log2(e): softmax in exp2 domain (exact wrt softmax)
#define QSCALE (0.17677669529663687f * 1.4426950408889634f)
#define HLS 264           // LDS h-tile row stride (elems)
#define AOS 264           // LDS ao-tile row stride (elems)
#define TLS 72            // LDS V-transpose tile row stride (elems; 144B, 16B-mult)

typedef unsigned short u16;
typedef unsigned int u32;
typedef __bf16 bf16x8 __attribute__((ext_vector_type(8)));
typedef float f32x4 __attribute__((ext_vector_type(4)));

__device__ __forceinline__ u16 f2bf(float f){
  union { float f; u32 i; } c; c.f = f;
  u32 x = c.i;
  return (u16)((x + 0x7fffu + ((x >> 16) & 1u)) >> 16);  // RNE
}

// ---------------------------------------------------------------------------
// lnqkv: fused LayerNorm + QKV GEMM (y = 0..2) + Wo transpose (y = 3).
// Q,K written row-major (qb, kb). V written TRANSPOSED: vt[d_full][node]
// ([256][4096] bf16) via an in-block LDS transpose (barrier-synced -- the
// legal form of the transpose; r8's barrier-free version raced). Values are
// bit-identical to the row-major path (same acc+bias, same f2bf); only the
// storage layout changes, so attnproj's V-fragment reads become contiguous.
__global__ __launch_bounds__(256) void lnqkv_kernel(
    const float* __restrict__ x, const float* __restrict__ gamma,
    const float* __restrict__ beta,
    const float* __restrict__ Wq, const float* __restrict__ Wk,
    const float* __restrict__ Wv, const float* __restrict__ Wo,
    const float* __restrict__ bq, const float* __restrict__ bk,
    const float* __restrict__ bv,
    u16* __restrict__ qb, u16* __restrict__ kb, u16* __restrict__ vt,
    u16* __restrict__ WoT){
  __shared__ u16 hl[64][HLS];
  int bid = blockIdx.x;            // 0..255
  int which = blockIdx.y;          // 0 = Q, 1 = K, 2 = V, 3 = Wo transpose
  if (which == 3){
    if (bid >= 64) return;
    u16 (*tl)[33] = (u16(*)[33])hl;
    int bx = (bid & 7) * 32, by = (bid >> 3) * 32;
    int tx = threadIdx.x & 31, ty = threadIdx.x >> 5;   // 32 x 8
    #pragma unroll
    for (int r = 0; r < 32; r += 8)
      tl[ty + r][tx] = f2bf(Wo[(size_t)(by + ty + r) * HID + bx + tx]);
    __syncthreads();
    #pragma unroll
    for (int r = 0; r < 32; r += 8)
      WoT[(size_t)(bx + ty + r) * HID + by + tx] = tl[tx][ty + r];
    return;
  }
  int wave = threadIdx.x >> 6, lane = threadIdx.x & 63;
  int m0 = (bid >> 2) * 64;                  // 64-row tile
  int nb = (bid & 3) * 64 + wave * 16;       // wave's 16-col slice
  const float* W    = (which == 0) ? Wq : (which == 1) ? Wk : Wv;
  const float* bias = (which == 0) ? bq : (which == 1) ? bk : bv;

  // ---- LN: wave handles rows wave*16..+15, 4 rows at a time.
  int rsub = lane >> 4;
  int c16  = lane & 15;
  float4 g0 = *(const float4*)(gamma + c16 * 16 + 0);
  float4 g1 = *(const float4*)(gamma + c16 * 16 + 4);
  float4 g2 = *(const float4*)(gamma + c16 * 16 + 8);
  float4 g3 = *(const float4*)(gamma + c16 * 16 + 12);
  float4 t0 = *(const float4*)(beta + c16 * 16 + 0);
  float4 t1 = *(const float4*)(beta + c16 * 16 + 4);
  float4 t2 = *(const float4*)(beta + c16 * 16 + 8);
  float4 t3 = *(const float4*)(beta + c16 * 16 + 12);
  float ga[16] = {g0.x,g0.y,g0.z,g0.w, g1.x,g1.y,g1.z,g1.w,
                  g2.x,g2.y,g2.z,g2.w, g3.x,g3.y,g3.z,g3.w};
  float bt[16] = {t0.x,t0.y,t0.z,t0.w, t1.x,t1.y,t1.z,t1.w,
                  t2.x,t2.y,t2.z,t2.w, t3.x,t3.y,t3.z,t3.w};
  #pragma unroll
  for (int b = 0; b < 4; b++){
    int rloc = wave * 16 + b * 4 + rsub;
    const float* xr = x + (size_t)(m0 + rloc) * HID + c16 * 16;
    float4 v0 = *(const float4*)(xr + 0);
    float4 v1 = *(const float4*)(xr + 4);
    float4 v2 = *(const float4*)(xr + 8);
    float4 v3 = *(const float4*)(xr + 12);
    float e[16] = {v0.x,v0.y,v0.z,v0.w, v1.x,v1.y,v1.z,v1.w,
                   v2.x,v2.y,v2.z,v2.w, v3.x,v3.y,v3.z,v3.w};
    float s = 0.f;
    #pragma unroll
    for (int i = 0; i < 16; i++) s += e[i];
    s += __shfl_xor(s, 1); s += __shfl_xor(s, 2);
    s += __shfl_xor(s, 4); s += __shfl_xor(s, 8);
    float mu = s * (1.0f / HID);
    float vv = 0.f;
    #pragma unroll
    for (int i = 0; i < 16; i++){ e[i] -= mu; vv += e[i] * e[i]; }
    vv += __shfl_xor(vv, 1); vv += __shfl_xor(vv, 2);
    vv += __shfl_xor(vv, 4); vv += __shfl_xor(vv, 8);
    float rs = rsqrtf(vv * (1.0f / HID) + LN_EPS);
    u32 pk[8];
    #pragma unroll
    for (int i = 0; i < 8; i++){
      float o0 = e[2*i]     * rs * ga[2*i]     + bt[2*i];
      float o1 = e[2*i + 1] * rs * ga[2*i + 1] + bt[2*i + 1];
      pk[i] = (u32)f2bf(o0) | ((u32)f2bf(o1) << 16);
    }
    *(uint4*)&hl[rloc][c16 * 16]     = make_uint4(pk[0], pk[1], pk[2], pk[3]);
    *(uint4*)&hl[rloc][c16 * 16 + 8] = make_uint4(pk[4], pk[5], pk[6], pk[7]);
  }
  __syncthreads();

  // ---- GEMM: wave = 64m x 16n; A from LDS h-tile, B from f32 W (strided).
  int lr = lane & 15, lq = lane >> 4;
  f32x4 acc[4] = {};
  const float* wbase = W + nb + lr;
  #pragma unroll
  for (int k0 = 0; k0 < HID; k0 += 32){
    union { bf16x8 v; u16 e[8]; } bf;
    const float* wp = wbase + (size_t)(k0 + lq * 8) * HID;
    #pragma unroll
    for (int j = 0; j < 8; j++) bf.e[j] = f2bf(wp[(size_t)j * HID]);
    #pragma unroll
    for (int t = 0; t < 4; t++){
      bf16x8 a = *(const bf16x8*)&hl[t * 16 + lr][k0 + lq * 8];
      acc[t] = __builtin_amdgcn_mfma_f32_16x16x32_bf16(a, bf.v, acc[t], 0, 0, 0);
    }
  }
  float bb = bias[nb + lr];
  if (which != 2){
    u16* out = (which == 0) ? qb : kb;
    int col = nb + lr;
    #pragma unroll
    for (int t = 0; t < 4; t++){
      #pragma unroll
      for (int r = 0; r < 4; r++){
        int row = m0 + 16 * t + lq * 4 + r;
        out[(size_t)row * HID + col] = f2bf(acc[t][r] + bb);
      }
    }
  } else {
    // ---- V: LDS transpose (barriers!) then coalesced V^T global stores.
    // tl[col_local (0..63)][row_local (0..63)], stride TLS.
    u16* tlb = &hl[0][0];
    __syncthreads();                  // all waves done reading hl
    #pragma unroll
    for (int t = 0; t < 4; t++){
      u32 lo = (u32)f2bf(acc[t][0] + bb) | ((u32)f2bf(acc[t][1] + bb) << 16);
      u32 hi = (u32)f2bf(acc[t][2] + bb) | ((u32)f2bf(acc[t][3] + bb) << 16);
      u16* rowp = tlb + (size_t)(wave * 16 + lr) * TLS + 16 * t + lq * 4;
      *(u32*)rowp       = lo;
      *(u32*)(rowp + 2) = hi;
    }
    __syncthreads();
    int nb0 = (bid & 3) * 64;
    int c  = threadIdx.x >> 3;        // 0..31
    int r8 = (threadIdx.x & 7) * 8;   // 0..56
    #pragma unroll
    for (int cc = 0; cc < 64; cc += 32){
      uint4 val = *(uint4*)&tlb[(size_t)(cc + c) * TLS + r8];
      *(uint4*)&vt[(size_t)(nb0 + cc + c) * NNODES + m0 + r8] = val;
    }
  }
}

// ---------------------------------------------------------------------------
// attnproj: fused flash attention + output projection + residual (r10/r11-
// passed architecture). v3: V fragments from the TRANSPOSED vt[d][node]
// buffer -- two contiguous 8B uint2 loads per tile instead of 8 scattered
// stride-512B scalar loads (the diagnosed VMEM-addressing-throughput cost).
// jstart is tile-aligned down (&~15): extra leading j are masked by lo_r
// (batch < g_lo there); tail clamp jal<=4092 keeps reads in-buffer and
// finite (masked positions contribute P=0 exactly). seg-table register
// masks + one-tile-ahead prefetch retained from r11.
__global__ __launch_bounds__(1024, 4) void attnproj_kernel(
    const u16* __restrict__ q, const u16* __restrict__ k,
    const u16* __restrict__ vt, const u16* __restrict__ WoT,
    const float* __restrict__ bo, const float* __restrict__ x,
    const int* __restrict__ batch, int bstride, float* __restrict__ out){
  __shared__ u16 ao[16][AOS];           // attention out [q][hid], bf16
  __shared__ float mg[8][10][64];       // merge: [head][o0x4,o1x4,m,l][lane]
  __shared__ int seg[NG + 1];
  int m0 = blockIdx.x * 16;
  int tid = threadIdx.x;
  int wave = tid >> 6, lane = tid & 63;
  // ---- seg table: wave w computes lower_bound(batch, w+1) -> seg[w+1]
  {
    int target = wave + 1;
    int p = batch[(size_t)(lane * 64) * bstride];
    int c = __popcll(__ballot(p < target));
    int lo = 0;
    if (c > 0){
      int base = (c - 1) * 64 + 1;
      int idx = base + lane;
      int val = (idx < NNODES) ? batch[(size_t)idx * bstride] : 0x7fffffff;
      lo = base + __popcll(__ballot(val < target));
    }
    if (lane == 0) seg[target] = lo;
    if (tid == 0) seg[0] = 0;
  }
  __syncthreads();
  int lq = lane >> 4, lr = lane & 15;
  int hd = wave & 7;                    // head
  int jh = wave >> 3;                   // j-half

  // ---- per-row graph bounds (hoisted; in-loop mask is register compares)
  int qrow = m0 + lr;
  int gq = batch[(size_t)qrow * bstride];
  int lo_r = seg[gq], hi_r = seg[gq + 1];
  int g_lo = batch[(size_t)m0 * bstride];
  int g_hi = batch[(size_t)(m0 + 15) * bstride];
  int jstart = seg[g_lo] & ~15;         // tile-aligned; leading j masked by lo_r
  int jend = seg[g_hi + 1];
  int ntj = (jend - jstart + 15) >> 4;  // >= 1 (covers own 16 rows)

  bf16x8 qf = *(const bf16x8*)&q[(size_t)qrow * HID + hd * HD + lq * 8];
  float m = -3.0e38f, l = 0.f;
  f32x4 o0 = {0.f,0.f,0.f,0.f}, o1 = {0.f,0.f,0.f,0.f};
  {
    int half = (ntj + 1) >> 1;
    int jt0 = jh ? half : 0;
    int jt1 = jh ? ntj : half;
    if (jt0 < jt1){
      const u16* vrow0 = vt + (size_t)(hd * HD + lr) * NNODES;
      const u16* vrow1 = vt + (size_t)(hd * HD + 16 + lr) * NNODES;
      auto LOADT = [&](int jt, bf16x8& kf, uint2& w0, uint2& w1){
        int j0 = jstart + (jt << 4);
        int krow = j0 + lr; if (krow > NNODES - 1) krow = NNODES - 1;
        kf = *(const bf16x8*)&k[(size_t)krow * HID + hd * HD + lq * 8];
        int jal = j0 + lq * 4;
        if (jal > NNODES - 4) jal = NNODES - 4;   // masked-only tail; finite data
        w0 = *(const uint2*)(vrow0 + jal);
        w1 = *(const uint2*)(vrow1 + jal);
      };
      bf16x8 kf_c; uint2 v0_c, v1_c;
      LOADT(jt0, kf_c, v0_c, v1_c);
      for (int jt = jt0; jt < jt1; jt++){
        // prefetch next tile (last iter re-loads current: harmless, branchless)
        bf16x8 kf_n; uint2 v0_n, v1_n;
        int jn = (jt + 1 < jt1) ? jt + 1 : jt;
        LOADT(jn, kf_n, v0_n, v1_n);
        int j0 = jstart + (jt << 4);
        f32x4 st = __builtin_amdgcn_mfma_f32_16x16x32_bf16(kf_c, qf,
                     (f32x4){0.f,0.f,0.f,0.f}, 0, 0, 0);
        int jb = j0 + lq * 4;
        // register-only graph mask: batch[j]==gq  <=>  lo_r <= j < hi_r
        float s0 = (jb + 0 >= lo_r && jb + 0 < hi_r) ? st[0] * QSCALE : -3.0e38f;
        float s1 = (jb + 1 >= lo_r && jb + 1 < hi_r) ? st[1] * QSCALE : -3.0e38f;
        float s2 = (jb + 2 >= lo_r && jb + 2 < hi_r) ? st[2] * QSCALE : -3.0e38f;
        float s3 = (jb + 3 >= lo_r && jb + 3 < hi_r) ? st[3] * QSCALE : -3.0e38f;
        float tm = fmaxf(fmaxf(s0, s1), fmaxf(s2, s3));
        tm = fmaxf(tm, __shfl_xor(tm, 16));
        tm = fmaxf(tm, __shfl_xor(tm, 32));
        float mn = fmaxf(m, tm);
        float alpha = exp2f(m - mn);       // first/empty tile: exp2(-huge) = 0
        float p0 = exp2f(s0 - mn), p1 = exp2f(s1 - mn);
        float p2 = exp2f(s2 - mn), p3 = exp2f(s3 - mn);
        float ps = (p0 + p1) + (p2 + p3);
        ps += __shfl_xor(ps, 16);
        ps += __shfl_xor(ps, 32);
        l = l * alpha + ps;
        m = mn;
        union { bf16x8 v8; u32 w[4]; } pf, vf0, vf1;
        pf.w[0] = (u32)f2bf(p0) | ((u32)f2bf(p1) << 16);
        pf.w[1] = (u32)f2bf(p2) | ((u32)f2bf(p3) << 16);
        pf.w[2] = 0; pf.w[3] = 0;
        vf0.w[0] = v0_c.x; vf0.w[1] = v0_c.y;
        vf0.w[2] = 0; vf0.w[3] = 0;
        vf1.w[0] = v1_c.x; vf1.w[1] = v1_c.y;
        vf1.w[2] = 0; vf1.w[3] = 0;
        o0 = o0 * alpha;
        o1 = o1 * alpha;
        o0 = __builtin_amdgcn_mfma_f32_16x16x32_bf16(vf0.v8, pf.v8, o0, 0, 0, 0);
        o1 = __builtin_amdgcn_mfma_f32_16x16x32_bf16(vf1.v8, pf.v8, o1, 0, 0, 0);
        kf_c = kf_n; v0_c = v0_n; v1_c = v1_n;
      }
    }
  }
  // j-half 1 publishes its partial state
  if (jh == 1){
    mg[hd][0][lane] = o0[0]; mg[hd][1][lane] = o0[1];
    mg[hd][2][lane] = o0[2]; mg[hd][3][lane] = o0[3];
    mg[hd][4][lane] = o1[0]; mg[hd][5][lane] = o1[1];
    mg[hd][6][lane] = o1[2]; mg[hd][7][lane] = o1[3];
    mg[hd][8][lane] = m;     mg[hd][9][lane] = l;
  }
  __syncthreads();
  // j-half 0 merges (exact flash combine), normalizes, writes ao tile.
  // Every q-row's diagonal is valid in one half -> that half's l >= 1 at its
  // own max -> lt >= 1 (empty halves contribute exactly 0).
  if (jh == 0){
    float m2 = mg[hd][8][lane], l2 = mg[hd][9][lane];
    float mn = fmaxf(m, m2);
    float a  = exp2f(m - mn);
    float a2 = exp2f(m2 - mn);
    float lt = l * a + l2 * a2;
    float rl = 1.0f / lt;
    float r0 = (o0[0]*a + mg[hd][0][lane]*a2) * rl;
    float r1 = (o0[1]*a + mg[hd][1][lane]*a2) * rl;
    float r2 = (o0[2]*a + mg[hd][2][lane]*a2) * rl;
    float r3 = (o0[3]*a + mg[hd][3][lane]*a2) * rl;
    float r4 = (o1[0]*a + mg[hd][4][lane]*a2) * rl;
    float r5 = (o1[1]*a + mg[hd][5][lane]*a2) * rl;
    float r6 = (o1[2]*a + mg[hd][6][lane]*a2) * rl;
    float r7 = (o1[3]*a + mg[hd][7][lane]*a2) * rl;
    int dbase = hd * HD + lq * 4;
    *(u32*)&ao[lr][dbase]          = (u32)f2bf(r0) | ((u32)f2bf(r1) << 16);
    *(u32*)&ao[lr][dbase + 2]      = (u32)f2bf(r2) | ((u32)f2bf(r3) << 16);
    *(u32*)&ao[lr][dbase + 16]     = (u32)f2bf(r4) | ((u32)f2bf(r5) << 16);
    *(u32*)&ao[lr][dbase + 16 + 2] = (u32)f2bf(r6) | ((u32)f2bf(r7) << 16);
  }
  __syncthreads();

  // ---- proj: 16 waves x 16 cols each; C = ao @ WoT^T + bo + x (f32)
  {
    int n0 = wave * 16;
    f32x4 acc = {};
    const u16* brow = WoT + (size_t)(n0 + lr) * HID + lq * 8;
    #pragma unroll
    for (int k0 = 0; k0 < HID; k0 += 32){
      bf16x8 a = *(const bf16x8*)&ao[lr][k0 + lq * 8];
      bf16x8 b = *(const bf16x8*)(brow + k0);
      acc = __builtin_amdgcn_mfma_f32_16x16x32_bf16(a, b, acc, 0, 0, 0);
    }
    int col = n0 + lr;
    float bb = bo[col];
    #pragma unroll
    for (int r = 0; r < 4; r++){
      size_t idx = (size_t)(m0 + lq * 4 + r) * HID + col;
      out[idx] = acc[r] + bb + x[idx];
    }
  }
}

// ---------------------------------------------------------------------------
// ws_size guard: paint an unmistakable sentinel if scratch is insufficient.
__global__ void sentinel_kernel(u32* __restrict__ out, int nwords){
  int i = blockIdx.x * 256 + threadIdx.x;
  if (i < nwords) out[i] = 0x46404640u;
}

// ---------------------------------------------------------------------------
extern "C" void kernel_launch(void* const* d_in, const int* in_sizes, int n_in,
                              void* d_out, int out_size, void* d_ws, size_t ws_size,
                              hipStream_t stream){
  const float* x   = (const float*)d_in[0];
  const int* batch = (const int*)d_in[1];
  const float* Wq = (const float*)d_in[2],  *bq = (const float*)d_in[3];
  const float* Wk = (const float*)d_in[4],  *bk = (const float*)d_in[5];
  const float* Wv = (const float*)d_in[6],  *bv = (const float*)d_in[7];
  const float* Wo = (const float*)d_in[8],  *bo = (const float*)d_in[9];
  const float* gamma = (const float*)d_in[10], *beta = (const float*)d_in[11];

  const size_t BUF  = (size_t)NNODES * HID * 2;   // 2 MB each (bf16)
  const size_t WOT  = (size_t)HID * HID * 2;      // 128 KB
  const size_t NEED = 1024 + 3 * BUF + WOT;       // ~6.4 MB

  if (ws_size < NEED){
    int nwords = out_size / 2;
    sentinel_kernel<<<(nwords + 255) / 256, 256, 0, stream>>>((u32*)d_out, nwords);
    return;
  }

  // batch dtype from the harness-reported byte size: int64 -> stride 2.
  int bstride = (in_sizes[1] >= NNODES * 8) ? 2 : 1;

  char* w = (char*)d_ws;
  u16* qb  = (u16*)(w + 1024);
  u16* kb  = qb + (size_t)NNODES * HID;
  u16* vt  = kb + (size_t)NNODES * HID;           // V^T [256][4096]
  u16* WoT = vt + (size_t)NNODES * HID;

  lnqkv_kernel<<<dim3(256, 4), 256, 0, stream>>>(x, gamma, beta, Wq, Wk, Wv, Wo,
                                                 bq, bk, bv, qb, kb, vt, WoT);
  attnproj_kernel<<<256, 1024, 0, stream>>>(qb, kb, vt, WoT, bo, x, batch,
                                            bstride, (float*)d_out);
}

// Round 14
// 116.183 us; speedup vs baseline: 1.0294x; 1.0294x over previous
//
#include <hip/hip_runtime.h>

#define NNODES 4096
#define HID 256
#define NG 16
#define NH 8
#define HD 32
#define LN_EPS 1e-5f
// (1/sqrt(32)) * log2(e): softmax in exp2 domain (exact wrt softmax)
#define QSCALE (0.17677669529663687f * 1.4426950408889634f)
#define HLS 264           // LDS h-tile row stride (elems)
#define AOS 264           // LDS ao-tile row stride (elems)

typedef unsigned short u16;
typedef unsigned int u32;
typedef __bf16 bf16x8 __attribute__((ext_vector_type(8)));
typedef float f32x4 __attribute__((ext_vector_type(4)));

__device__ __forceinline__ u16 f2bf(float f){
  union { float f; u32 i; } c; c.f = f;
  u32 x = c.i;
  return (u16)((x + 0x7fffu + ((x >> 16) & 1u)) >> 16);  // RNE
}

// ---------------------------------------------------------------------------
// lnqkv: fused LayerNorm + QKV GEMM (y = 0..2; r11-passed verbatim) +
// Wo transpose (y = 3, bid < 64; WoT[n][k] = f2bf(Wo[k][n])).
__global__ __launch_bounds__(256) void lnqkv_kernel(
    const float* __restrict__ x, const float* __restrict__ gamma,
    const float* __restrict__ beta,
    const float* __restrict__ Wq, const float* __restrict__ Wk,
    const float* __restrict__ Wv, const float* __restrict__ Wo,
    const float* __restrict__ bq, const float* __restrict__ bk,
    const float* __restrict__ bv,
    u16* __restrict__ qb, u16* __restrict__ kb, u16* __restrict__ vb,
    u16* __restrict__ WoT){
  __shared__ u16 hl[64][HLS];
  int bid = blockIdx.x;            // 0..255
  int which = blockIdx.y;          // 0 = Q, 1 = K, 2 = V, 3 = Wo transpose
  if (which == 3){
    if (bid >= 64) return;
    u16 (*tl)[33] = (u16(*)[33])hl;
    int bx = (bid & 7) * 32, by = (bid >> 3) * 32;
    int tx = threadIdx.x & 31, ty = threadIdx.x >> 5;   // 32 x 8
    #pragma unroll
    for (int r = 0; r < 32; r += 8)
      tl[ty + r][tx] = f2bf(Wo[(size_t)(by + ty + r) * HID + bx + tx]);
    __syncthreads();
    #pragma unroll
    for (int r = 0; r < 32; r += 8)
      WoT[(size_t)(bx + ty + r) * HID + by + tx] = tl[tx][ty + r];
    return;
  }
  int wave = threadIdx.x >> 6, lane = threadIdx.x & 63;
  int m0 = (bid >> 2) * 64;                  // 64-row tile
  int nb = (bid & 3) * 64 + wave * 16;       // wave's 16-col slice
  const float* W    = (which == 0) ? Wq : (which == 1) ? Wk : Wv;
  const float* bias = (which == 0) ? bq : (which == 1) ? bk : bv;
  u16* out          = (which == 0) ? qb : (which == 1) ? kb : vb;

  // ---- LN: wave handles rows wave*16..+15, 4 rows at a time.
  int rsub = lane >> 4;
  int c16  = lane & 15;
  float4 g0 = *(const float4*)(gamma + c16 * 16 + 0);
  float4 g1 = *(const float4*)(gamma + c16 * 16 + 4);
  float4 g2 = *(const float4*)(gamma + c16 * 16 + 8);
  float4 g3 = *(const float4*)(gamma + c16 * 16 + 12);
  float4 t0 = *(const float4*)(beta + c16 * 16 + 0);
  float4 t1 = *(const float4*)(beta + c16 * 16 + 4);
  float4 t2 = *(const float4*)(beta + c16 * 16 + 8);
  float4 t3 = *(const float4*)(beta + c16 * 16 + 12);
  float ga[16] = {g0.x,g0.y,g0.z,g0.w, g1.x,g1.y,g1.z,g1.w,
                  g2.x,g2.y,g2.z,g2.w, g3.x,g3.y,g3.z,g3.w};
  float bt[16] = {t0.x,t0.y,t0.z,t0.w, t1.x,t1.y,t1.z,t1.w,
                  t2.x,t2.y,t2.z,t2.w, t3.x,t3.y,t3.z,t3.w};
  #pragma unroll
  for (int b = 0; b < 4; b++){
    int rloc = wave * 16 + b * 4 + rsub;
    const float* xr = x + (size_t)(m0 + rloc) * HID + c16 * 16;
    float4 v0 = *(const float4*)(xr + 0);
    float4 v1 = *(const float4*)(xr + 4);
    float4 v2 = *(const float4*)(xr + 8);
    float4 v3 = *(const float4*)(xr + 12);
    float e[16] = {v0.x,v0.y,v0.z,v0.w, v1.x,v1.y,v1.z,v1.w,
                   v2.x,v2.y,v2.z,v2.w, v3.x,v3.y,v3.z,v3.w};
    float s = 0.f;
    #pragma unroll
    for (int i = 0; i < 16; i++) s += e[i];
    s += __shfl_xor(s, 1); s += __shfl_xor(s, 2);
    s += __shfl_xor(s, 4); s += __shfl_xor(s, 8);
    float mu = s * (1.0f / HID);
    float vv = 0.f;
    #pragma unroll
    for (int i = 0; i < 16; i++){ e[i] -= mu; vv += e[i] * e[i]; }
    vv += __shfl_xor(vv, 1); vv += __shfl_xor(vv, 2);
    vv += __shfl_xor(vv, 4); vv += __shfl_xor(vv, 8);
    float rs = rsqrtf(vv * (1.0f / HID) + LN_EPS);
    u32 pk[8];
    #pragma unroll
    for (int i = 0; i < 8; i++){
      float o0 = e[2*i]     * rs * ga[2*i]     + bt[2*i];
      float o1 = e[2*i + 1] * rs * ga[2*i + 1] + bt[2*i + 1];
      pk[i] = (u32)f2bf(o0) | ((u32)f2bf(o1) << 16);
    }
    *(uint4*)&hl[rloc][c16 * 16]     = make_uint4(pk[0], pk[1], pk[2], pk[3]);
    *(uint4*)&hl[rloc][c16 * 16 + 8] = make_uint4(pk[4], pk[5], pk[6], pk[7]);
  }
  __syncthreads();

  // ---- GEMM: wave = 64m x 16n; A from LDS h-tile, B from f32 W (strided).
  int lr = lane & 15, lq = lane >> 4;
  f32x4 acc[4] = {};
  const float* wbase = W + nb + lr;
  #pragma unroll
  for (int k0 = 0; k0 < HID; k0 += 32){
    union { bf16x8 v; u16 e[8]; } bf;
    const float* wp = wbase + (size_t)(k0 + lq * 8) * HID;
    #pragma unroll
    for (int j = 0; j < 8; j++) bf.e[j] = f2bf(wp[(size_t)j * HID]);
    #pragma unroll
    for (int t = 0; t < 4; t++){
      bf16x8 a = *(const bf16x8*)&hl[t * 16 + lr][k0 + lq * 8];
      acc[t] = __builtin_amdgcn_mfma_f32_16x16x32_bf16(a, bf.v, acc[t], 0, 0, 0);
    }
  }
  int col = nb + lr;
  float bb = bias[col];
  #pragma unroll
  for (int t = 0; t < 4; t++){
    #pragma unroll
    for (int r = 0; r < 4; r++){
      int row = m0 + 16 * t + lq * 4 + r;
      out[(size_t)row * HID + col] = f2bf(acc[t][r] + bb);
    }
  }
}

// ---------------------------------------------------------------------------
// attnproj: fused flash attention + output projection + residual. r11-passed
// base (seg-table register masks, one-tile-ahead prefetch, register-V,
// direct-global K, exact flash merge, LDS ao -> proj vs WoT). v4 changes:
//  (1) deferred l-reduction: the cross-lane ps sum (2 shfl/tile in the serial
//      chain) is removed; l is a per-lane partial (exact: alpha is uniform
//      across each 4-lane q-column group) and the 2-shfl sum happens ONCE in
//      the merge.
//  (2) XCD-chunked tile mapping: tile = (bid&7)*32 + bid>>3, so each XCD's
//      round-robin share is 32 consecutive q-tiles (~2 graphs) -> K/V L2
//      locality instead of 8-way cross-XCD duplication. Bijective.
__global__ __launch_bounds__(1024, 4) void attnproj_kernel(
    const u16* __restrict__ q, const u16* __restrict__ k,
    const u16* __restrict__ v, const u16* __restrict__ WoT,
    const float* __restrict__ bo, const float* __restrict__ x,
    const int* __restrict__ batch, int bstride, float* __restrict__ out){
  __shared__ u16 ao[16][AOS];           // attention out [q][hid], bf16
  __shared__ float mg[8][10][64];       // merge: [head][o0x4,o1x4,m,l][lane]
  __shared__ int seg[NG + 1];
  int bid = blockIdx.x;
  int tile = ((bid & 7) << 5) | (bid >> 3);   // XCD-chunked (bijective, 256)
  int m0 = tile * 16;
  int tid = threadIdx.x;
  int wave = tid >> 6, lane = tid & 63;
  // ---- seg table: wave w computes lower_bound(batch, w+1) -> seg[w+1]
  {
    int target = wave + 1;
    int p = batch[(size_t)(lane * 64) * bstride];
    int c = __popcll(__ballot(p < target));
    int lo = 0;
    if (c > 0){
      int base = (c - 1) * 64 + 1;
      int idx = base + lane;
      int val = (idx < NNODES) ? batch[(size_t)idx * bstride] : 0x7fffffff;
      lo = base + __popcll(__ballot(val < target));
    }
    if (lane == 0) seg[target] = lo;
    if (tid == 0) seg[0] = 0;
  }
  __syncthreads();
  int lq = lane >> 4, lr = lane & 15;
  int hd = wave & 7;                    // head
  int jh = wave >> 3;                   // j-half

  // ---- per-row graph bounds (hoisted; in-loop mask is register compares)
  int qrow = m0 + lr;
  int gq = batch[(size_t)qrow * bstride];
  int lo_r = seg[gq], hi_r = seg[gq + 1];
  int g_lo = batch[(size_t)m0 * bstride];
  int g_hi = batch[(size_t)(m0 + 15) * bstride];
  int jstart = seg[g_lo];
  int jend = seg[g_hi + 1];
  int ntj = (jend - jstart + 15) >> 4;  // >= 1 (covers own 16 rows)

  bf16x8 qf = *(const bf16x8*)&q[(size_t)qrow * HID + hd * HD + lq * 8];
  float m = -3.0e38f, l = 0.f;          // l is a PER-LANE partial (v4)
  f32x4 o0 = {0.f,0.f,0.f,0.f}, o1 = {0.f,0.f,0.f,0.f};
  {
    int half = (ntj + 1) >> 1;
    int jt0 = jh ? half : 0;
    int jt1 = jh ? ntj : half;
    if (jt0 < jt1){
      auto LOADT = [&](int jt, bf16x8& kf, u16* va, u16* vc){
        int j0 = jstart + (jt << 4);
        int krow = j0 + lr; if (krow > NNODES - 1) krow = NNODES - 1;
        kf = *(const bf16x8*)&k[(size_t)krow * HID + hd * HD + lq * 8];
        #pragma unroll
        for (int i = 0; i < 4; i++){
          int vrow = j0 + lq * 4 + i;
          if (vrow > NNODES - 1) vrow = NNODES - 1;
          const u16* vp = &v[(size_t)vrow * HID + hd * HD + lr];
          va[i] = vp[0];
          vc[i] = vp[16];
        }
      };
      bf16x8 kf_c; u16 va_c[4], vc_c[4];
      LOADT(jt0, kf_c, va_c, vc_c);
      for (int jt = jt0; jt < jt1; jt++){
        // prefetch next tile (last iter re-loads current: harmless, branchless)
        bf16x8 kf_n; u16 va_n[4], vc_n[4];
        int jn = (jt + 1 < jt1) ? jt + 1 : jt;
        LOADT(jn, kf_n, va_n, vc_n);
        int j0 = jstart + (jt << 4);
        f32x4 st = __builtin_amdgcn_mfma_f32_16x16x32_bf16(kf_c, qf,
                     (f32x4){0.f,0.f,0.f,0.f}, 0, 0, 0);
        int jb = j0 + lq * 4;
        // register-only graph mask: batch[j]==gq  <=>  lo_r <= j < hi_r
        float s0 = (jb + 0 >= lo_r && jb + 0 < hi_r) ? st[0] * QSCALE : -3.0e38f;
        float s1 = (jb + 1 >= lo_r && jb + 1 < hi_r) ? st[1] * QSCALE : -3.0e38f;
        float s2 = (jb + 2 >= lo_r && jb + 2 < hi_r) ? st[2] * QSCALE : -3.0e38f;
        float s3 = (jb + 3 >= lo_r && jb + 3 < hi_r) ? st[3] * QSCALE : -3.0e38f;
        float tm = fmaxf(fmaxf(s0, s1), fmaxf(s2, s3));
        tm = fmaxf(tm, __shfl_xor(tm, 16));
        tm = fmaxf(tm, __shfl_xor(tm, 32));
        float mn = fmaxf(m, tm);
        float alpha = exp2f(m - mn);       // first/empty tile: exp2(-huge) = 0
        float p0 = exp2f(s0 - mn), p1 = exp2f(s1 - mn);
        float p2 = exp2f(s2 - mn), p3 = exp2f(s3 - mn);
        // deferred reduction: per-lane partial only (alpha uniform per group)
        l = l * alpha + ((p0 + p1) + (p2 + p3));
        m = mn;
        union { bf16x8 v8; u32 w[4]; } pf, vf0, vf1;
        pf.w[0] = (u32)f2bf(p0) | ((u32)f2bf(p1) << 16);
        pf.w[1] = (u32)f2bf(p2) | ((u32)f2bf(p3) << 16);
        pf.w[2] = 0; pf.w[3] = 0;
        vf0.w[0] = (u32)va_c[0] | ((u32)va_c[1] << 16);
        vf0.w[1] = (u32)va_c[2] | ((u32)va_c[3] << 16);
        vf0.w[2] = 0; vf0.w[3] = 0;
        vf1.w[0] = (u32)vc_c[0] | ((u32)vc_c[1] << 16);
        vf1.w[1] = (u32)vc_c[2] | ((u32)vc_c[3] << 16);
        vf1.w[2] = 0; vf1.w[3] = 0;
        o0 = o0 * alpha;
        o1 = o1 * alpha;
        o0 = __builtin_amdgcn_mfma_f32_16x16x32_bf16(vf0.v8, pf.v8, o0, 0, 0, 0);
        o1 = __builtin_amdgcn_mfma_f32_16x16x32_bf16(vf1.v8, pf.v8, o1, 0, 0, 0);
        kf_c = kf_n;
        #pragma unroll
        for (int i = 0; i < 4; i++){ va_c[i] = va_n[i]; vc_c[i] = vc_n[i]; }
      }
    }
  }
  // j-half 1 publishes its partial state (l is per-lane partial)
  if (jh == 1){
    mg[hd][0][lane] = o0[0]; mg[hd][1][lane] = o0[1];
    mg[hd][2][lane] = o0[2]; mg[hd][3][lane] = o0[3];
    mg[hd][4][lane] = o1[0]; mg[hd][5][lane] = o1[1];
    mg[hd][6][lane] = o1[2]; mg[hd][7][lane] = o1[3];
    mg[hd][8][lane] = m;     mg[hd][9][lane] = l;
  }
  __syncthreads();
  // j-half 0 merges (exact flash combine), reduces l across the 4-lane
  // q-column group ONCE, normalizes, writes ao tile. m/m2 are uniform per
  // group, so a/a2 are too; lt partial-sum then 2 shfls gives the total.
  if (jh == 0){
    float m2 = mg[hd][8][lane], l2 = mg[hd][9][lane];
    float mn = fmaxf(m, m2);
    float a  = exp2f(m - mn);
    float a2 = exp2f(m2 - mn);
    float lt = l * a + l2 * a2;         // per-lane partial
    lt += __shfl_xor(lt, 16);
    lt += __shfl_xor(lt, 32);           // total over j (>= 1: diagonal)
    float rl = 1.0f / lt;
    float r0 = (o0[0]*a + mg[hd][0][lane]*a2) * rl;
    float r1 = (o0[1]*a + mg[hd][1][lane]*a2) * rl;
    float r2 = (o0[2]*a + mg[hd][2][lane]*a2) * rl;
    float r3 = (o0[3]*a + mg[hd][3][lane]*a2) * rl;
    float r4 = (o1[0]*a + mg[hd][4][lane]*a2) * rl;
    float r5 = (o1[1]*a + mg[hd][5][lane]*a2) * rl;
    float r6 = (o1[2]*a + mg[hd][6][lane]*a2) * rl;
    float r7 = (o1[3]*a + mg[hd][7][lane]*a2) * rl;
    int dbase = hd * HD + lq * 4;
    *(u32*)&ao[lr][dbase]          = (u32)f2bf(r0) | ((u32)f2bf(r1) << 16);
    *(u32*)&ao[lr][dbase + 2]      = (u32)f2bf(r2) | ((u32)f2bf(r3) << 16);
    *(u32*)&ao[lr][dbase + 16]     = (u32)f2bf(r4) | ((u32)f2bf(r5) << 16);
    *(u32*)&ao[lr][dbase + 16 + 2] = (u32)f2bf(r6) | ((u32)f2bf(r7) << 16);
  }
  __syncthreads();

  // ---- proj: 16 waves x 16 cols each; C = ao @ WoT^T + bo + x (f32)
  {
    int n0 = wave * 16;
    f32x4 acc = {};
    const u16* brow = WoT + (size_t)(n0 + lr) * HID + lq * 8;
    #pragma unroll
    for (int k0 = 0; k0 < HID; k0 += 32){
      bf16x8 a = *(const bf16x8*)&ao[lr][k0 + lq * 8];
      bf16x8 b = *(const bf16x8*)(brow + k0);
      acc = __builtin_amdgcn_mfma_f32_16x16x32_bf16(a, b, acc, 0, 0, 0);
    }
    int col = n0 + lr;
    float bb = bo[col];
    #pragma unroll
    for (int r = 0; r < 4; r++){
      size_t idx = (size_t)(m0 + lq * 4 + r) * HID + col;
      out[idx] = acc[r] + bb + x[idx];
    }
  }
}

// ---------------------------------------------------------------------------
// ws_size guard: paint an unmistakable sentinel if scratch is insufficient.
__global__ void sentinel_kernel(u32* __restrict__ out, int nwords){
  int i = blockIdx.x * 256 + threadIdx.x;
  if (i < nwords) out[i] = 0x46404640u;
}

// ---------------------------------------------------------------------------
extern "C" void kernel_launch(void* const* d_in, const int* in_sizes, int n_in,
                              void* d_out, int out_size, void* d_ws, size_t ws_size,
                              hipStream_t stream){
  const float* x   = (const float*)d_in[0];
  const int* batch = (const int*)d_in[1];
  const float* Wq = (const float*)d_in[2],  *bq = (const float*)d_in[3];
  const float* Wk = (const float*)d_in[4],  *bk = (const float*)d_in[5];
  const float* Wv = (const float*)d_in[6],  *bv = (const float*)d_in[7];
  const float* Wo = (const float*)d_in[8],  *bo = (const float*)d_in[9];
  const float* gamma = (const float*)d_in[10], *beta = (const float*)d_in[11];

  const size_t BUF  = (size_t)NNODES * HID * 2;   // 2 MB each (bf16)
  const size_t WOT  = (size_t)HID * HID * 2;      // 128 KB
  const size_t NEED = 1024 + 3 * BUF + WOT;       // ~6.4 MB

  if (ws_size < NEED){
    int nwords = out_size / 2;
    sentinel_kernel<<<(nwords + 255) / 256, 256, 0, stream>>>((u32*)d_out, nwords);
    return;
  }

  // batch dtype from the harness-reported byte size: int64 -> stride 2.
  int bstride = (in_sizes[1] >= NNODES * 8) ? 2 : 1;

  char* w = (char*)d_ws;
  u16* qb  = (u16*)(w + 1024);
  u16* kb  = qb + (size_t)NNODES * HID;
  u16* vb  = kb + (size_t)NNODES * HID;
  u16* WoT = vb + (size_t)NNODES * HID;

  lnqkv_kernel<<<dim3(256, 4), 256, 0, stream>>>(x, gamma, beta, Wq, Wk, Wv, Wo,
                                                 bq, bk, bv, qb, kb, vb, WoT);
  attnproj_kernel<<<256, 1024, 0, stream>>>(qb, kb, vb, WoT, bo, x, batch,
                                            bstride, (float*)d_out);
}

// Round 15
// 112.881 us; speedup vs baseline: 1.0595x; 1.0292x over previous
//
#include <hip/hip_runtime.h>

#define NNODES 4096
#define HID 256
#define NG 16
#define NH 8
#define HD 32
#define LN_EPS 1e-5f
// (1/sqrt(32)) * log2(e): softmax in exp2 domain (exact wrt softmax)
#define QSCALE (0.17677669529663687f * 1.4426950408889634f)
#define HLS 264           // LDS h-tile row stride (elems)
#define AOS 264           // LDS ao-tile row stride (elems)

typedef unsigned short u16;
typedef unsigned int u32;
typedef __bf16 bf16x8 __attribute__((ext_vector_type(8)));
typedef float f32x4 __attribute__((ext_vector_type(4)));

__device__ __forceinline__ u16 f2bf(float f){
  union { float f; u32 i; } c; c.f = f;
  u32 x = c.i;
  return (u16)((x + 0x7fffu + ((x >> 16) & 1u)) >> 16);  // RNE
}

// ---------------------------------------------------------------------------
// lnqkv: fused LayerNorm + QKV GEMM (y = 0..2) + Wo transpose (y = 3).
// r11-passed verbatim (session best: 113.3 us).
__global__ __launch_bounds__(256) void lnqkv_kernel(
    const float* __restrict__ x, const float* __restrict__ gamma,
    const float* __restrict__ beta,
    const float* __restrict__ Wq, const float* __restrict__ Wk,
    const float* __restrict__ Wv, const float* __restrict__ Wo,
    const float* __restrict__ bq, const float* __restrict__ bk,
    const float* __restrict__ bv,
    u16* __restrict__ qb, u16* __restrict__ kb, u16* __restrict__ vb,
    u16* __restrict__ WoT){
  __shared__ u16 hl[64][HLS];
  int bid = blockIdx.x;            // 0..255
  int which = blockIdx.y;          // 0 = Q, 1 = K, 2 = V, 3 = Wo transpose
  if (which == 3){
    if (bid >= 64) return;
    u16 (*tl)[33] = (u16(*)[33])hl;
    int bx = (bid & 7) * 32, by = (bid >> 3) * 32;
    int tx = threadIdx.x & 31, ty = threadIdx.x >> 5;   // 32 x 8
    #pragma unroll
    for (int r = 0; r < 32; r += 8)
      tl[ty + r][tx] = f2bf(Wo[(size_t)(by + ty + r) * HID + bx + tx]);
    __syncthreads();
    #pragma unroll
    for (int r = 0; r < 32; r += 8)
      WoT[(size_t)(bx + ty + r) * HID + by + tx] = tl[tx][ty + r];
    return;
  }
  int wave = threadIdx.x >> 6, lane = threadIdx.x & 63;
  int m0 = (bid >> 2) * 64;                  // 64-row tile
  int nb = (bid & 3) * 64 + wave * 16;       // wave's 16-col slice
  const float* W    = (which == 0) ? Wq : (which == 1) ? Wk : Wv;
  const float* bias = (which == 0) ? bq : (which == 1) ? bk : bv;
  u16* out          = (which == 0) ? qb : (which == 1) ? kb : vb;

  // ---- LN: wave handles rows wave*16..+15, 4 rows at a time.
  int rsub = lane >> 4;
  int c16  = lane & 15;
  float4 g0 = *(const float4*)(gamma + c16 * 16 + 0);
  float4 g1 = *(const float4*)(gamma + c16 * 16 + 4);
  float4 g2 = *(const float4*)(gamma + c16 * 16 + 8);
  float4 g3 = *(const float4*)(gamma + c16 * 16 + 12);
  float4 t0 = *(const float4*)(beta + c16 * 16 + 0);
  float4 t1 = *(const float4*)(beta + c16 * 16 + 4);
  float4 t2 = *(const float4*)(beta + c16 * 16 + 8);
  float4 t3 = *(const float4*)(beta + c16 * 16 + 12);
  float ga[16] = {g0.x,g0.y,g0.z,g0.w, g1.x,g1.y,g1.z,g1.w,
                  g2.x,g2.y,g2.z,g2.w, g3.x,g3.y,g3.z,g3.w};
  float bt[16] = {t0.x,t0.y,t0.z,t0.w, t1.x,t1.y,t1.z,t1.w,
                  t2.x,t2.y,t2.z,t2.w, t3.x,t3.y,t3.z,t3.w};
  #pragma unroll
  for (int b = 0; b < 4; b++){
    int rloc = wave * 16 + b * 4 + rsub;
    const float* xr = x + (size_t)(m0 + rloc) * HID + c16 * 16;
    float4 v0 = *(const float4*)(xr + 0);
    float4 v1 = *(const float4*)(xr + 4);
    float4 v2 = *(const float4*)(xr + 8);
    float4 v3 = *(const float4*)(xr + 12);
    float e[16] = {v0.x,v0.y,v0.z,v0.w, v1.x,v1.y,v1.z,v1.w,
                   v2.x,v2.y,v2.z,v2.w, v3.x,v3.y,v3.z,v3.w};
    float s = 0.f;
    #pragma unroll
    for (int i = 0; i < 16; i++) s += e[i];
    s += __shfl_xor(s, 1); s += __shfl_xor(s, 2);
    s += __shfl_xor(s, 4); s += __shfl_xor(s, 8);
    float mu = s * (1.0f / HID);
    float vv = 0.f;
    #pragma unroll
    for (int i = 0; i < 16; i++){ e[i] -= mu; vv += e[i] * e[i]; }
    vv += __shfl_xor(vv, 1); vv += __shfl_xor(vv, 2);
    vv += __shfl_xor(vv, 4); vv += __shfl_xor(vv, 8);
    float rs = rsqrtf(vv * (1.0f / HID) + LN_EPS);
    u32 pk[8];
    #pragma unroll
    for (int i = 0; i < 8; i++){
      float o0 = e[2*i]     * rs * ga[2*i]     + bt[2*i];
      float o1 = e[2*i + 1] * rs * ga[2*i + 1] + bt[2*i + 1];
      pk[i] = (u32)f2bf(o0) | ((u32)f2bf(o1) << 16);
    }
    *(uint4*)&hl[rloc][c16 * 16]     = make_uint4(pk[0], pk[1], pk[2], pk[3]);
    *(uint4*)&hl[rloc][c16 * 16 + 8] = make_uint4(pk[4], pk[5], pk[6], pk[7]);
  }
  __syncthreads();

  // ---- GEMM: wave = 64m x 16n; A from LDS h-tile, B from f32 W (strided).
  int lr = lane & 15, lq = lane >> 4;
  f32x4 acc[4] = {};
  const float* wbase = W + nb + lr;
  #pragma unroll
  for (int k0 = 0; k0 < HID; k0 += 32){
    union { bf16x8 v; u16 e[8]; } bf;
    const float* wp = wbase + (size_t)(k0 + lq * 8) * HID;
    #pragma unroll
    for (int j = 0; j < 8; j++) bf.e[j] = f2bf(wp[(size_t)j * HID]);
    #pragma unroll
    for (int t = 0; t < 4; t++){
      bf16x8 a = *(const bf16x8*)&hl[t * 16 + lr][k0 + lq * 8];
      acc[t] = __builtin_amdgcn_mfma_f32_16x16x32_bf16(a, bf.v, acc[t], 0, 0, 0);
    }
  }
  int col = nb + lr;
  float bb = bias[col];
  #pragma unroll
  for (int t = 0; t < 4; t++){
    #pragma unroll
    for (int r = 0; r < 4; r++){
      int row = m0 + 16 * t + lq * 4 + r;
      out[(size_t)row * HID + col] = f2bf(acc[t][r] + bb);
    }
  }
}

// ---------------------------------------------------------------------------
// attnproj: fused flash attention + output projection + residual.
// r11-passed verbatim (session best): seg-table register masks, one-tile-
// ahead K/V prefetch into registers, direct-global K, register-V (8 strided
// u16 loads -- the r9-proven race-free path), wave-pair j-split with exact
// LDS flash merge, ao tile in LDS feeding the 16-wave proj GEMM vs WoT.
__global__ __launch_bounds__(1024, 4) void attnproj_kernel(
    const u16* __restrict__ q, const u16* __restrict__ k,
    const u16* __restrict__ v, const u16* __restrict__ WoT,
    const float* __restrict__ bo, const float* __restrict__ x,
    const int* __restrict__ batch, int bstride, float* __restrict__ out){
  __shared__ u16 ao[16][AOS];           // attention out [q][hid], bf16
  __shared__ float mg[8][10][64];       // merge: [head][o0x4,o1x4,m,l][lane]
  __shared__ int seg[NG + 1];
  int m0 = blockIdx.x * 16;
  int tid = threadIdx.x;
  int wave = tid >> 6, lane = tid & 63;
  // ---- seg table: wave w computes lower_bound(batch, w+1) -> seg[w+1]
  {
    int target = wave + 1;
    int p = batch[(size_t)(lane * 64) * bstride];
    int c = __popcll(__ballot(p < target));
    int lo = 0;
    if (c > 0){
      int base = (c - 1) * 64 + 1;
      int idx = base + lane;
      int val = (idx < NNODES) ? batch[(size_t)idx * bstride] : 0x7fffffff;
      lo = base + __popcll(__ballot(val < target));
    }
    if (lane == 0) seg[target] = lo;
    if (tid == 0) seg[0] = 0;
  }
  __syncthreads();
  int lq = lane >> 4, lr = lane & 15;
  int hd = wave & 7;                    // head
  int jh = wave >> 3;                   // j-half

  // ---- per-row graph bounds (hoisted; in-loop mask is register compares)
  int qrow = m0 + lr;
  int gq = batch[(size_t)qrow * bstride];
  int lo_r = seg[gq], hi_r = seg[gq + 1];
  int g_lo = batch[(size_t)m0 * bstride];
  int g_hi = batch[(size_t)(m0 + 15) * bstride];
  int jstart = seg[g_lo];
  int jend = seg[g_hi + 1];
  int ntj = (jend - jstart + 15) >> 4;  // >= 1 (covers own 16 rows)

  bf16x8 qf = *(const bf16x8*)&q[(size_t)qrow * HID + hd * HD + lq * 8];
  float m = -3.0e38f, l = 0.f;
  f32x4 o0 = {0.f,0.f,0.f,0.f}, o1 = {0.f,0.f,0.f,0.f};
  {
    int half = (ntj + 1) >> 1;
    int jt0 = jh ? half : 0;
    int jt1 = jh ? ntj : half;
    if (jt0 < jt1){
      auto LOADT = [&](int jt, bf16x8& kf, u16* va, u16* vc){
        int j0 = jstart + (jt << 4);
        int krow = j0 + lr; if (krow > NNODES - 1) krow = NNODES - 1;
        kf = *(const bf16x8*)&k[(size_t)krow * HID + hd * HD + lq * 8];
        #pragma unroll
        for (int i = 0; i < 4; i++){
          int vrow = j0 + lq * 4 + i;
          if (vrow > NNODES - 1) vrow = NNODES - 1;
          const u16* vp = &v[(size_t)vrow * HID + hd * HD + lr];
          va[i] = vp[0];
          vc[i] = vp[16];
        }
      };
      bf16x8 kf_c; u16 va_c[4], vc_c[4];
      LOADT(jt0, kf_c, va_c, vc_c);
      for (int jt = jt0; jt < jt1; jt++){
        // prefetch next tile (last iter re-loads current: harmless, branchless)
        bf16x8 kf_n; u16 va_n[4], vc_n[4];
        int jn = (jt + 1 < jt1) ? jt + 1 : jt;
        LOADT(jn, kf_n, va_n, vc_n);
        int j0 = jstart + (jt << 4);
        f32x4 st = __builtin_amdgcn_mfma_f32_16x16x32_bf16(kf_c, qf,
                     (f32x4){0.f,0.f,0.f,0.f}, 0, 0, 0);
        int jb = j0 + lq * 4;
        // register-only graph mask: batch[j]==gq  <=>  lo_r <= j < hi_r
        float s0 = (jb + 0 >= lo_r && jb + 0 < hi_r) ? st[0] * QSCALE : -3.0e38f;
        float s1 = (jb + 1 >= lo_r && jb + 1 < hi_r) ? st[1] * QSCALE : -3.0e38f;
        float s2 = (jb + 2 >= lo_r && jb + 2 < hi_r) ? st[2] * QSCALE : -3.0e38f;
        float s3 = (jb + 3 >= lo_r && jb + 3 < hi_r) ? st[3] * QSCALE : -3.0e38f;
        float tm = fmaxf(fmaxf(s0, s1), fmaxf(s2, s3));
        tm = fmaxf(tm, __shfl_xor(tm, 16));
        tm = fmaxf(tm, __shfl_xor(tm, 32));
        float mn = fmaxf(m, tm);
        float alpha = exp2f(m - mn);       // first/empty tile: exp2(-huge) = 0
        float p0 = exp2f(s0 - mn), p1 = exp2f(s1 - mn);
        float p2 = exp2f(s2 - mn), p3 = exp2f(s3 - mn);
        float ps = (p0 + p1) + (p2 + p3);
        ps += __shfl_xor(ps, 16);
        ps += __shfl_xor(ps, 32);
        l = l * alpha + ps;
        m = mn;
        union { bf16x8 v8; u32 w[4]; } pf, vf0, vf1;
        pf.w[0] = (u32)f2bf(p0) | ((u32)f2bf(p1) << 16);
        pf.w[1] = (u32)f2bf(p2) | ((u32)f2bf(p3) << 16);
        pf.w[2] = 0; pf.w[3] = 0;
        vf0.w[0] = (u32)va_c[0] | ((u32)va_c[1] << 16);
        vf0.w[1] = (u32)va_c[2] | ((u32)va_c[3] << 16);
        vf0.w[2] = 0; vf0.w[3] = 0;
        vf1.w[0] = (u32)vc_c[0] | ((u32)vc_c[1] << 16);
        vf1.w[1] = (u32)vc_c[2] | ((u32)vc_c[3] << 16);
        vf1.w[2] = 0; vf1.w[3] = 0;
        o0 = o0 * alpha;
        o1 = o1 * alpha;
        o0 = __builtin_amdgcn_mfma_f32_16x16x32_bf16(vf0.v8, pf.v8, o0, 0, 0, 0);
        o1 = __builtin_amdgcn_mfma_f32_16x16x32_bf16(vf1.v8, pf.v8, o1, 0, 0, 0);
        kf_c = kf_n;
        #pragma unroll
        for (int i = 0; i < 4; i++){ va_c[i] = va_n[i]; vc_c[i] = vc_n[i]; }
      }
    }
  }
  // j-half 1 publishes its partial state
  if (jh == 1){
    mg[hd][0][lane] = o0[0]; mg[hd][1][lane] = o0[1];
    mg[hd][2][lane] = o0[2]; mg[hd][3][lane] = o0[3];
    mg[hd][4][lane] = o1[0]; mg[hd][5][lane] = o1[1];
    mg[hd][6][lane] = o1[2]; mg[hd][7][lane] = o1[3];
    mg[hd][8][lane] = m;     mg[hd][9][lane] = l;
  }
  __syncthreads();
  // j-half 0 merges (exact flash combine), normalizes, writes ao tile.
  // Every q-row's diagonal is valid in one half -> that half's l >= 1 at its
  // own max -> lt >= 1 (empty halves contribute exactly 0).
  if (jh == 0){
    float m2 = mg[hd][8][lane], l2 = mg[hd][9][lane];
    float mn = fmaxf(m, m2);
    float a  = exp2f(m - mn);
    float a2 = exp2f(m2 - mn);
    float lt = l * a + l2 * a2;
    float rl = 1.0f / lt;
    float r0 = (o0[0]*a + mg[hd][0][lane]*a2) * rl;
    float r1 = (o0[1]*a + mg[hd][1][lane]*a2) * rl;
    float r2 = (o0[2]*a + mg[hd][2][lane]*a2) * rl;
    float r3 = (o0[3]*a + mg[hd][3][lane]*a2) * rl;
    float r4 = (o1[0]*a + mg[hd][4][lane]*a2) * rl;
    float r5 = (o1[1]*a + mg[hd][5][lane]*a2) * rl;
    float r6 = (o1[2]*a + mg[hd][6][lane]*a2) * rl;
    float r7 = (o1[3]*a + mg[hd][7][lane]*a2) * rl;
    int dbase = hd * HD + lq * 4;
    *(u32*)&ao[lr][dbase]          = (u32)f2bf(r0) | ((u32)f2bf(r1) << 16);
    *(u32*)&ao[lr][dbase + 2]      = (u32)f2bf(r2) | ((u32)f2bf(r3) << 16);
    *(u32*)&ao[lr][dbase + 16]     = (u32)f2bf(r4) | ((u32)f2bf(r5) << 16);
    *(u32*)&ao[lr][dbase + 16 + 2] = (u32)f2bf(r6) | ((u32)f2bf(r7) << 16);
  }
  __syncthreads();

  // ---- proj: 16 waves x 16 cols each; C = ao @ WoT^T + bo + x (f32)
  {
    int n0 = wave * 16;
    f32x4 acc = {};
    const u16* brow = WoT + (size_t)(n0 + lr) * HID + lq * 8;
    #pragma unroll
    for (int k0 = 0; k0 < HID; k0 += 32){
      bf16x8 a = *(const bf16x8*)&ao[lr][k0 + lq * 8];
      bf16x8 b = *(const bf16x8*)(brow + k0);
      acc = __builtin_amdgcn_mfma_f32_16x16x32_bf16(a, b, acc, 0, 0, 0);
    }
    int col = n0 + lr;
    float bb = bo[col];
    #pragma unroll
    for (int r = 0; r < 4; r++){
      size_t idx = (size_t)(m0 + lq * 4 + r) * HID + col;
      out[idx] = acc[r] + bb + x[idx];
    }
  }
}

// ---------------------------------------------------------------------------
// ws_size guard: paint an unmistakable sentinel if scratch is insufficient.
__global__ void sentinel_kernel(u32* __restrict__ out, int nwords){
  int i = blockIdx.x * 256 + threadIdx.x;
  if (i < nwords) out[i] = 0x46404640u;
}

// ---------------------------------------------------------------------------
extern "C" void kernel_launch(void* const* d_in, const int* in_sizes, int n_in,
                              void* d_out, int out_size, void* d_ws, size_t ws_size,
                              hipStream_t stream){
  const float* x   = (const float*)d_in[0];
  const int* batch = (const int*)d_in[1];
  const float* Wq = (const float*)d_in[2],  *bq = (const float*)d_in[3];
  const float* Wk = (const float*)d_in[4],  *bk = (const float*)d_in[5];
  const float* Wv = (const float*)d_in[6],  *bv = (const float*)d_in[7];
  const float* Wo = (const float*)d_in[8],  *bo = (const float*)d_in[9];
  const float* gamma = (const float*)d_in[10], *beta = (const float*)d_in[11];

  const size_t BUF  = (size_t)NNODES * HID * 2;   // 2 MB each (bf16)
  const size_t WOT  = (size_t)HID * HID * 2;      // 128 KB
  const size_t NEED = 1024 + 3 * BUF + WOT;       // ~6.4 MB

  if (ws_size < NEED){
    int nwords = out_size / 2;
    sentinel_kernel<<<(nwords + 255) / 256, 256, 0, stream>>>((u32*)d_out, nwords);
    return;
  }

  // batch dtype from the harness-reported byte size: int64 -> stride 2.
  int bstride = (in_sizes[1] >= NNODES * 8) ? 2 : 1;

  char* w = (char*)d_ws;
  u16* qb  = (u16*)(w + 1024);
  u16* kb  = qb + (size_t)NNODES * HID;
  u16* vb  = kb + (size_t)NNODES * HID;
  u16* WoT = vb + (size_t)NNODES * HID;

  lnqkv_kernel<<<dim3(256, 4), 256, 0, stream>>>(x, gamma, beta, Wq, Wk, Wv, Wo,
                                                 bq, bk, bv, qb, kb, vb, WoT);
  attnproj_kernel<<<256, 1024, 0, stream>>>(qb, kb, vb, WoT, bo, x, batch,
                                            bstride, (float*)d_out);
}